// Round 2
// baseline (989.623 us; speedup 1.0000x reference)
//
#include <hip/hip_runtime.h>
#include <stdint.h>

typedef __attribute__((ext_vector_type(8))) short short8;
typedef __attribute__((ext_vector_type(4))) float f32x4;

__device__ __forceinline__ unsigned short f2bf(float f) {
  union { float f; unsigned int i; } v; v.f = f;
  return (unsigned short)((v.i + 0x7FFFu + ((v.i >> 16) & 1u)) >> 16);
}
__device__ __forceinline__ float hswish(float x) {
  float t = fminf(fmaxf(x + 3.f, 0.f), 6.f);
  return x * t * (1.f / 6.f);
}
// load 8 consecutive fp32 from global, convert to bf16 fragment
__device__ __forceinline__ short8 ldcvt8(const float* __restrict__ p) {
  float4 v0 = *(const float4*)p;
  float4 v1 = *(const float4*)(p + 4);
  short8 r;
  r[0] = (short)f2bf(v0.x); r[1] = (short)f2bf(v0.y);
  r[2] = (short)f2bf(v0.z); r[3] = (short)f2bf(v0.w);
  r[4] = (short)f2bf(v1.x); r[5] = (short)f2bf(v1.y);
  r[6] = (short)f2bf(v1.z); r[7] = (short)f2bf(v1.w);
  return r;
}

// ---------------------------------------------------------------------------
// Prep: cw -> cwLT bf16 (m = j*128+i layout); L1/L2 -> tril bf16
// ---------------------------------------------------------------------------
__global__ void prep_kernel(const float* __restrict__ cw0, const float* __restrict__ cw1,
                            const float* __restrict__ cw2,
                            const float* __restrict__ L1_0, const float* __restrict__ L2_0,
                            const float* __restrict__ L1_1, const float* __restrict__ L2_1,
                            const float* __restrict__ L1_2, const float* __restrict__ L2_2,
                            unsigned short* __restrict__ ws16) {
  // ws16 element offsets (bf16 units):
  // cwLT0 @0 (16384), cwLT1 @16384 (32768), cwLT2 @49152 (65536),
  // L1b0 @114688 (16384), L2b0 @131072, L1b1 @147456 (4096), L2b1 @151552,
  // L1b2 @155648 (1024), L2b2 @156672; total 157696
  int idx = blockIdx.x * 256 + threadIdx.x;
  if (idx < 16384) {
    ws16[idx] = f2bf(cw0[idx]);                      // k=1: identity layout
  } else if (idx < 49152) {
    int t = idx - 16384; int o = t >> 8, m = t & 255, j = m >> 7, i = m & 127;
    ws16[idx] = f2bf(cw1[(o * 128 + i) * 2 + j]);
  } else if (idx < 114688) {
    int t = idx - 49152; int o = t >> 9, m = t & 511, j = m >> 7, i = m & 127;
    ws16[idx] = f2bf(cw2[(o * 128 + i) * 4 + j]);
  } else if (idx < 131072) {
    int u = idx - 114688; int t = u >> 7, s = u & 127;
    ws16[idx] = (s <= t) ? f2bf(L1_0[u]) : (unsigned short)0;
  } else if (idx < 147456) {
    int u = idx - 131072; int t = u >> 7, s = u & 127;
    ws16[idx] = (s <= t) ? f2bf(L2_0[u]) : (unsigned short)0;
  } else if (idx < 151552) {
    int u = idx - 147456; int t = u >> 6, s = u & 63;
    ws16[idx] = (s <= t) ? f2bf(L1_1[u]) : (unsigned short)0;
  } else if (idx < 155648) {
    int u = idx - 151552; int t = u >> 6, s = u & 63;
    ws16[idx] = (s <= t) ? f2bf(L2_1[u]) : (unsigned short)0;
  } else if (idx < 156672) {
    int u = idx - 155648; int t = u >> 5, s = u & 31;
    ws16[idx] = (s <= t) ? f2bf(L1_2[u]) : (unsigned short)0;
  } else if (idx < 157696) {
    int u = idx - 156672; int t = u >> 5, s = u & 31;
    ws16[idx] = (s <= t) ? f2bf(L2_2[u]) : (unsigned short)0;
  }
}

// ---------------------------------------------------------------------------
// Fused stage 1: one block per sample, all three scales.
// ---------------------------------------------------------------------------
template <int S>
__device__ __forceinline__ void scale_pass(
    const float* __restrict__ xn,
    const float* __restrict__ cb, const float* __restrict__ lg, const float* __restrict__ lb,
    const unsigned short* __restrict__ cwLT,
    const unsigned short* __restrict__ L1b, const unsigned short* __restrict__ L2b,
    unsigned short* __restrict__ HT, float* __restrict__ scr, float* __restrict__ part,
    float* __restrict__ hout, float fcb,
    int wave, int lane, int quad, int l16, int tid) {
  constexpr int K  = 128 << S;
  constexpr int TK = 128 >> S;
  constexpr int nT = (S == 0) ? 4 : (S == 1) ? 2 : 1;
  constexpr int NK = K / 32;
  constexpr int NTK = TK / 32;
  constexpr int CMASK = TK / 8 - 1;

  const int Tb = (wave & 1) * nT;   // t-tile base
  const int Ob = (wave >> 1) * 4;   // o-tile base (4 tiles per wave)

  __syncthreads();                  // prev scale's part reads done
  if (tid < TK) part[tid] = 0.f;

  f32x4 acc[nT][4];
#pragma unroll
  for (int tt = 0; tt < nT; ++tt)
#pragma unroll
    for (int oo = 0; oo < 4; ++oo) acc[tt][oo] = (f32x4){0.f, 0.f, 0.f, 0.f};

  // ---- conv: barrier-free, A from global x (fp32->bf16), B from cwLT ----
#pragma unroll
  for (int ks = 0; ks < NK; ++ks) {
    short8 a[nT];
#pragma unroll
    for (int tt = 0; tt < nT; ++tt) {
      int t = (Tb + tt) * 16 + l16;
      a[tt] = ldcvt8(xn + t * K + ks * 32 + quad * 8);
    }
#pragma unroll
    for (int oo = 0; oo < 4; ++oo) {
      int o = (Ob + oo) * 16 + l16;
      short8 b = *(const short8*)&cwLT[o * K + ks * 32 + quad * 8];
#pragma unroll
      for (int tt = 0; tt < nT; ++tt)
        acc[tt][oo] = __builtin_amdgcn_mfma_f32_16x16x32_bf16(a[tt], b, acc[tt][oo], 0, 0, 0);
    }
  }

  // ---- +cb, LN stats ----
  float sum = 0.f, ss = 0.f;
#pragma unroll
  for (int oo = 0; oo < 4; ++oo) {
    float cbv = cb[(Ob + oo) * 16 + l16];
#pragma unroll
    for (int tt = 0; tt < nT; ++tt)
#pragma unroll
      for (int r = 0; r < 4; ++r) {
        float v = acc[tt][oo][r] + cbv;
        acc[tt][oo][r] = v;
        sum += v; ss += v * v;
      }
  }
#pragma unroll
  for (int m = 32; m >= 1; m >>= 1) { sum += __shfl_xor(sum, m); ss += __shfl_xor(ss, m); }
  if (lane == 0) { scr[256 + wave * 2] = sum; scr[257 + wave * 2] = ss; }
  __syncthreads();
  if (tid == 0) {
    float Sm = scr[256] + scr[258] + scr[260] + scr[262];
    float Sq = scr[257] + scr[259] + scr[261] + scr[263];
    float mu = Sm / (float)(TK * 128);
    float var = Sq / (float)(TK * 128) - mu * mu;
    scr[264] = mu; scr[265] = rsqrtf(var + 1e-5f);
  }
  __syncthreads();
  const float mu = scr[264], rsig = scr[265];

  // ---- fc contribution of xt ----
#pragma unroll
  for (int tt = 0; tt < nT; ++tt)
#pragma unroll
    for (int r = 0; r < 4; ++r) {
      float v = 0.f;
#pragma unroll
      for (int oo = 0; oo < 4; ++oo) v += acc[tt][oo][r] * scr[(Ob + oo) * 16 + l16];
      v += __shfl_xor(v, 1); v += __shfl_xor(v, 2);
      v += __shfl_xor(v, 4); v += __shfl_xor(v, 8);
      if (l16 == 0) atomicAdd(&part[(Tb + tt) * 16 + quad * 4 + r], v);
    }

  // ---- HT[f][t] = bf16(LN(xt)), XOR-swizzled chunks (releases acc) ----
#pragma unroll
  for (int tt = 0; tt < nT; ++tt)
#pragma unroll
    for (int oo = 0; oo < 4; ++oo) {
      int f = (Ob + oo) * 16 + l16;
      int kf = (f ^ (f >> 3)) & CMASK;
#pragma unroll
      for (int r = 0; r < 4; ++r) {
        int t = (Tb + tt) * 16 + quad * 4 + r;
        float hv = (acc[tt][oo][r] - mu) * rsig * lg[t * 128 + f] + lb[t * 128 + f];
        HT[f * TK + (((t >> 3) ^ kf) << 3) + (t & 7)] = f2bf(hv);
      }
    }
  __syncthreads();

  // ---- TM1: U = hswish(tril(L1) @ H), barrier-free loop ----
#pragma unroll
  for (int tt = 0; tt < nT; ++tt)
#pragma unroll
    for (int oo = 0; oo < 4; ++oo) acc[tt][oo] = (f32x4){0.f, 0.f, 0.f, 0.f};
#pragma unroll
  for (int ks = 0; ks < NTK; ++ks) {
    int k0 = ks * 32;
    if (k0 > (Tb + nT - 1) * 16 + 15) continue;
    short8 a[nT];
#pragma unroll
    for (int tt = 0; tt < nT; ++tt)
      if (k0 <= (Tb + tt) * 16 + 15) {
        int t = (Tb + tt) * 16 + l16;
        a[tt] = *(const short8*)&L1b[t * TK + k0 + quad * 8];
      }
#pragma unroll
    for (int oo = 0; oo < 4; ++oo) {
      int f = (Ob + oo) * 16 + l16;
      int kf = (f ^ (f >> 3)) & CMASK;
      short8 b = *(const short8*)&HT[f * TK + (((ks * 4 + quad) ^ kf) << 3)];
#pragma unroll
      for (int tt = 0; tt < nT; ++tt)
        if (k0 <= (Tb + tt) * 16 + 15)
          acc[tt][oo] = __builtin_amdgcn_mfma_f32_16x16x32_bf16(a[tt], b, acc[tt][oo], 0, 0, 0);
    }
  }
  __syncthreads();

  // ---- UT = bf16(hswish(U)) over HT ----
#pragma unroll
  for (int tt = 0; tt < nT; ++tt)
#pragma unroll
    for (int oo = 0; oo < 4; ++oo) {
      int f = (Ob + oo) * 16 + l16;
      int kf = (f ^ (f >> 3)) & CMASK;
#pragma unroll
      for (int r = 0; r < 4; ++r) {
        int t = (Tb + tt) * 16 + quad * 4 + r;
        HT[f * TK + (((t >> 3) ^ kf) << 3) + (t & 7)] = f2bf(hswish(acc[tt][oo][r]));
      }
    }
  __syncthreads();

  // ---- TM2: v = tril(L2) @ U ----
#pragma unroll
  for (int tt = 0; tt < nT; ++tt)
#pragma unroll
    for (int oo = 0; oo < 4; ++oo) acc[tt][oo] = (f32x4){0.f, 0.f, 0.f, 0.f};
#pragma unroll
  for (int ks = 0; ks < NTK; ++ks) {
    int k0 = ks * 32;
    if (k0 > (Tb + nT - 1) * 16 + 15) continue;
    short8 a[nT];
#pragma unroll
    for (int tt = 0; tt < nT; ++tt)
      if (k0 <= (Tb + tt) * 16 + 15) {
        int t = (Tb + tt) * 16 + l16;
        a[tt] = *(const short8*)&L2b[t * TK + k0 + quad * 8];
      }
#pragma unroll
    for (int oo = 0; oo < 4; ++oo) {
      int f = (Ob + oo) * 16 + l16;
      int kf = (f ^ (f >> 3)) & CMASK;
      short8 b = *(const short8*)&HT[f * TK + (((ks * 4 + quad) ^ kf) << 3)];
#pragma unroll
      for (int tt = 0; tt < nT; ++tt)
        if (k0 <= (Tb + tt) * 16 + 15)
          acc[tt][oo] = __builtin_amdgcn_mfma_f32_16x16x32_bf16(a[tt], b, acc[tt][oo], 0, 0, 0);
    }
  }

  // ---- fc contribution of v ----
#pragma unroll
  for (int tt = 0; tt < nT; ++tt)
#pragma unroll
    for (int r = 0; r < 4; ++r) {
      float v = 0.f;
#pragma unroll
      for (int oo = 0; oo < 4; ++oo) v += acc[tt][oo][r] * scr[(Ob + oo) * 16 + l16];
      v += __shfl_xor(v, 1); v += __shfl_xor(v, 2);
      v += __shfl_xor(v, 4); v += __shfl_xor(v, 8);
      if (l16 == 0) atomicAdd(&part[(Tb + tt) * 16 + quad * 4 + r], v);
    }
  __syncthreads();
  if (tid < TK) hout[tid] = part[tid] + fcb;
}

__launch_bounds__(256, 2)
__global__ void s1_fused(const float* __restrict__ x,
                         const float* __restrict__ cb0, const float* __restrict__ lg0, const float* __restrict__ lb0,
                         const float* __restrict__ cb1, const float* __restrict__ lg1, const float* __restrict__ lb1,
                         const float* __restrict__ cb2, const float* __restrict__ lg2, const float* __restrict__ lb2,
                         const float* __restrict__ fc_w, const float* __restrict__ fc_b,
                         const unsigned short* __restrict__ ws16,
                         float* __restrict__ h_out) {
  __shared__ unsigned short HT[128 * 128];
  __shared__ float scr[268];
  const int tid = threadIdx.x, wave = tid >> 6, lane = tid & 63;
  const int quad = lane >> 4, l16 = lane & 15;
  const int n = blockIdx.x;
  const float* xn = x + (size_t)n * 16384;
  if (tid < 128) scr[tid] = fc_w[tid];
  float* part = scr + 128;
  const float fcb = fc_b[0];
  float* hout = h_out + (size_t)n * 224;

  scale_pass<0>(xn, cb0, lg0, lb0, ws16, ws16 + 114688, ws16 + 131072,
                HT, scr, part, hout, fcb, wave, lane, quad, l16, tid);
  scale_pass<1>(xn, cb1, lg1, lb1, ws16 + 16384, ws16 + 147456, ws16 + 151552,
                HT, scr, part, hout + 128, fcb, wave, lane, quad, l16, tid);
  scale_pass<2>(xn, cb2, lg2, lb2, ws16 + 49152, ws16 + 155648, ws16 + 156672,
                HT, scr, part, hout + 192, fcb, wave, lane, quad, l16, tid);
}

// ---------------------------------------------------------------------------
// Stage 2 (unchanged)
// ---------------------------------------------------------------------------
__global__ void stats_kernel(const float* __restrict__ h, float* __restrict__ stats) {
  int base = blockIdx.x * 4096;
  float s = 0.f, ss = 0.f;
  for (int j = 0; j < 16; ++j) {
    float v = h[base + j * 256 + threadIdx.x];
    s += v; ss += v * v;
  }
  int lane = threadIdx.x & 63, wave = threadIdx.x >> 6;
#pragma unroll
  for (int m = 32; m >= 1; m >>= 1) { s += __shfl_xor(s, m); ss += __shfl_xor(ss, m); }
  __shared__ float red[8];
  if (lane == 0) { red[wave * 2] = s; red[wave * 2 + 1] = ss; }
  __syncthreads();
  if (threadIdx.x == 0) {
    atomicAdd(&stats[0], red[0] + red[2] + red[4] + red[6]);
    atomicAdd(&stats[1], red[1] + red[3] + red[5] + red[7]);
  }
}

__global__ void mix1_kernel(const float* __restrict__ h,
                            const float* __restrict__ sm_lg,
                            const float* __restrict__ sm_lb,
                            const float* __restrict__ M1,
                            const float* __restrict__ stats,
                            float* __restrict__ A) {
  const int m = blockIdx.x, seg = blockIdx.y;
  const int r = threadIdx.x & 63, ch = threadIdx.x >> 6;
  const float inv = 1.f / 917504.f;
  float mu = stats[0] * inv;
  float var = stats[1] * inv - mu * mu;
  float rsig = rsqrtf(var + 1e-5f);
  float acc = 0.f;
  int n0 = seg * 1024 + ch * 256;
  for (int i = 0; i < 256; ++i) {
    int n = n0 + i;
    float hn = (h[n * 224 + m] - mu) * rsig * sm_lg[n * 224 + m] + sm_lb[n * 224 + m];
    acc += M1[r * 4096 + n] * hn;
  }
  __shared__ float red[256];
  red[threadIdx.x] = acc;
  __syncthreads();
  if (threadIdx.x < 64)
    atomicAdd(&A[threadIdx.x * 224 + m],
              red[threadIdx.x] + red[64 + threadIdx.x] + red[128 + threadIdx.x] + red[192 + threadIdx.x]);
}

__global__ void mix2_kernel(const float* __restrict__ A,
                            const float* __restrict__ sm_fc_w,
                            float* __restrict__ cvec) {
  int r = threadIdx.x & 63, ch = threadIdx.x >> 6;
  float acc = 0.f;
  for (int j = ch; j < 224; j += 4)
    acc += hswish(A[r * 224 + j]) * sm_fc_w[224 + j];
  __shared__ float red[256];
  red[threadIdx.x] = acc;
  __syncthreads();
  if (threadIdx.x < 64)
    cvec[threadIdx.x] = red[threadIdx.x] + red[64 + threadIdx.x] + red[128 + threadIdx.x] + red[192 + threadIdx.x];
}

__global__ void out_kernel(const float* __restrict__ h,
                           const float* __restrict__ M2,
                           const float* __restrict__ cvec,
                           const float* __restrict__ sm_fc_w,
                           const float* __restrict__ sm_fc_b,
                           float* __restrict__ out) {
  int wave = threadIdx.x >> 6, lane = threadIdx.x & 63;
  int n = blockIdx.x * 4 + wave;
  float acc = M2[n * 64 + lane] * cvec[lane];
  for (int j = lane; j < 224; j += 64)
    acc += h[n * 224 + j] * (sm_fc_w[j] + sm_fc_w[224 + j]);
#pragma unroll
  for (int m = 32; m >= 1; m >>= 1) acc += __shfl_xor(acc, m);
  if (lane == 0) out[n] = acc + sm_fc_b[0];
}

// ---------------------------------------------------------------------------
extern "C" void kernel_launch(void* const* d_in, const int* in_sizes, int n_in,
                              void* d_out, int out_size, void* d_ws, size_t ws_size,
                              hipStream_t stream) {
  const float* x      = (const float*)d_in[0];
  const float* cw0    = (const float*)d_in[1];
  const float* cb0    = (const float*)d_in[2];
  const float* lg0    = (const float*)d_in[3];
  const float* lb0    = (const float*)d_in[4];
  const float* L1_0   = (const float*)d_in[5];
  const float* L2_0   = (const float*)d_in[6];
  const float* cw1    = (const float*)d_in[7];
  const float* cb1    = (const float*)d_in[8];
  const float* lg1    = (const float*)d_in[9];
  const float* lb1    = (const float*)d_in[10];
  const float* L1_1   = (const float*)d_in[11];
  const float* L2_1   = (const float*)d_in[12];
  const float* cw2    = (const float*)d_in[13];
  const float* cb2    = (const float*)d_in[14];
  const float* lg2    = (const float*)d_in[15];
  const float* lb2    = (const float*)d_in[16];
  const float* L1_2   = (const float*)d_in[17];
  const float* L2_2   = (const float*)d_in[18];
  const float* fc_w   = (const float*)d_in[19];
  const float* fc_b   = (const float*)d_in[20];
  const float* sm_lg  = (const float*)d_in[21];
  const float* sm_lb  = (const float*)d_in[22];
  const float* M1     = (const float*)d_in[23];
  const float* M2     = (const float*)d_in[24];
  const float* sm_fc_w = (const float*)d_in[25];
  const float* sm_fc_b = (const float*)d_in[26];

  char* ws = (char*)d_ws;
  unsigned short* ws16 = (unsigned short*)ws;        // 157696 bf16 elems = 315392 B
  float* h     = (float*)(ws + 315392);              // 3670016 B
  float* stats = (float*)(ws + 3985408);             // 8 B (+pad)
  float* A     = (float*)(ws + 3985664);             // 57344 B
  float* cvec  = (float*)(ws + 4043008);             // 256 B

  prep_kernel<<<616, 256, 0, stream>>>(cw0, cw1, cw2, L1_0, L2_0, L1_1, L2_1, L1_2, L2_2, ws16);

  s1_fused<<<4096, 256, 0, stream>>>(x, cb0, lg0, lb0, cb1, lg1, lb1, cb2, lg2, lb2,
                                     fc_w, fc_b, ws16, h);

  hipMemsetAsync(ws + 3985408, 0, 57600, stream);
  stats_kernel<<<224, 256, 0, stream>>>(h, stats);
  mix1_kernel<<<dim3(224, 4), 256, 0, stream>>>(h, sm_lg, sm_lb, M1, stats, A);
  mix2_kernel<<<1, 256, 0, stream>>>(A, sm_fc_w, cvec);
  out_kernel<<<1024, 256, 0, stream>>>(h, M2, cvec, sm_fc_w, sm_fc_b, (float*)d_out);
}

// Round 3
// 902.004 us; speedup vs baseline: 1.0971x; 1.0971x over previous
//
#include <hip/hip_runtime.h>
#include <stdint.h>

typedef __attribute__((ext_vector_type(8))) short short8;
typedef __attribute__((ext_vector_type(4))) float f32x4;
typedef __attribute__((ext_vector_type(4))) unsigned short us4;

__device__ __forceinline__ unsigned short f2bf(float f) {
  union { float f; unsigned int i; } v; v.f = f;
  return (unsigned short)((v.i + 0x7FFFu + ((v.i >> 16) & 1u)) >> 16);
}
__device__ __forceinline__ float hswish(float x) {
  float t = fminf(fmaxf(x + 3.f, 0.f), 6.f);
  return x * t * (1.f / 6.f);
}
__device__ __forceinline__ short8 ldcvt8(const float* __restrict__ p) {
  float4 v0 = *(const float4*)p;
  float4 v1 = *(const float4*)(p + 4);
  short8 r;
  r[0] = (short)f2bf(v0.x); r[1] = (short)f2bf(v0.y);
  r[2] = (short)f2bf(v0.z); r[3] = (short)f2bf(v0.w);
  r[4] = (short)f2bf(v1.x); r[5] = (short)f2bf(v1.y);
  r[6] = (short)f2bf(v1.z); r[7] = (short)f2bf(v1.w);
  return r;
}

// ---------------------------------------------------------------------------
// Prep: cw -> cwLT bf16 (m=j*128+i); L1/L2 -> block-diag tril 128x128 bf16
// ws16 offsets (bf16): cwLT0@0(16384) cwLT1@16384(32768) cwLT2@49152(65536)
//   L1b0@114688 L2b0@131072 L1b1@147456 L2b1@163840 L1b2@180224 L2b2@196608
// ---------------------------------------------------------------------------
__global__ void prep_kernel(const float* __restrict__ cw0, const float* __restrict__ cw1,
                            const float* __restrict__ cw2,
                            const float* __restrict__ L1_0, const float* __restrict__ L2_0,
                            const float* __restrict__ L1_1, const float* __restrict__ L2_1,
                            const float* __restrict__ L1_2, const float* __restrict__ L2_2,
                            unsigned short* __restrict__ ws16) {
  int idx = blockIdx.x * 256 + threadIdx.x;
  if (idx < 16384) {
    ws16[idx] = f2bf(cw0[idx]);
  } else if (idx < 49152) {
    int t = idx - 16384; int o = t >> 8, m = t & 255, j = m >> 7, i = m & 127;
    ws16[idx] = f2bf(cw1[(o * 128 + i) * 2 + j]);
  } else if (idx < 114688) {
    int t = idx - 49152; int o = t >> 9, m = t & 511, j = m >> 7, i = m & 127;
    ws16[idx] = f2bf(cw2[(o * 128 + i) * 4 + j]);
  } else if (idx < 212992) {
    int u = idx - 114688; int which = u >> 14; int e = u & 16383;
    int t = e >> 7, s = e & 127;
    float val = 0.f;
    if (which == 0)      { if (s <= t) val = L1_0[t * 128 + s]; }
    else if (which == 1) { if (s <= t) val = L2_0[t * 128 + s]; }
    else if (which == 2) { if ((s >> 6) == (t >> 6) && (s & 63) <= (t & 63)) val = L1_1[(t & 63) * 64 + (s & 63)]; }
    else if (which == 3) { if ((s >> 6) == (t >> 6) && (s & 63) <= (t & 63)) val = L2_1[(t & 63) * 64 + (s & 63)]; }
    else if (which == 4) { if ((s >> 5) == (t >> 5) && (s & 31) <= (t & 31)) val = L1_2[(t & 31) * 32 + (s & 31)]; }
    else                 { if ((s >> 5) == (t >> 5) && (s & 31) <= (t & 31)) val = L2_2[(t & 31) * 32 + (s & 31)]; }
    ws16[idx] = f2bf(val);
  }
}

// x (fp32, 268MB) -> xbf (bf16, 134MB)
__global__ void xcvt_kernel(const float* __restrict__ x, unsigned short* __restrict__ xbf) {
  const float4* x4 = (const float4*)x;
  us4* o4 = (us4*)xbf;
#pragma unroll
  for (int j = 0; j < 4; ++j) {
    int idx = blockIdx.x * 1024 + j * 256 + threadIdx.x;
    float4 v = x4[idx];
    us4 p; p[0] = f2bf(v.x); p[1] = f2bf(v.y); p[2] = f2bf(v.z); p[3] = f2bf(v.w);
    o4[idx] = p;
  }
}

template <bool XBF>
__device__ __forceinline__ short8 load_a(const float* __restrict__ xf,
                                         const unsigned short* __restrict__ xb, int off) {
  if constexpr (XBF) return *(const short8*)&xb[off];
  else return ldcvt8(xf + off);
}

// ---------------------------------------------------------------------------
// Stage 1: one block = 128 output rows = 2^S samples. conv -> LN -> TM1 -> TM2 -> fc.
// ---------------------------------------------------------------------------
template <int S, bool XBF>
__launch_bounds__(256, 3)
__global__ void s1_tile(const float* __restrict__ xf, const unsigned short* __restrict__ xb,
                        const float* __restrict__ cb, const float* __restrict__ lg,
                        const float* __restrict__ lb,
                        const float* __restrict__ fc_w, const float* __restrict__ fc_b,
                        const unsigned short* __restrict__ cwLT,
                        const unsigned short* __restrict__ L1blk,
                        const unsigned short* __restrict__ L2blk,
                        float* __restrict__ h_out) {
  constexpr int K = 128 << S;
  constexpr int LOG2TK = 7 - S;
  constexpr int TKM = (128 >> S) - 1;
  constexpr int SAMPLES = 1 << S;
  constexpr int OFF = (S == 0) ? 0 : (S == 1 ? 128 : 192);
  constexpr int NK = K / 32;
  constexpr int GSH = 3 - S;
  constexpr float INVD = 1.f / (float)((TKM + 1) * 128);

  __shared__ unsigned short HT[128 * 128];
  __shared__ float scr[272];
  // scr: [0..127] fcw, [128..255] part, [256..263] stat sums, [264..267] mu, [268..271] rsig
  float* part = scr + 128;

  const int tid = threadIdx.x, wave = tid >> 6, lane = tid & 63;
  const int quad = lane >> 4, l16 = lane & 15;
  const int Tb = (wave & 1) * 4, Ob = (wave >> 1) * 4;
  const int n0 = blockIdx.x << S;
  const int abase = n0 * 16384;
  const float fcb = fc_b[0];

  if (tid < 128) { scr[tid] = fc_w[tid]; part[tid] = 0.f; }
  else if (tid < 144) scr[tid + 128] = 0.f;
  __syncthreads();

  // ---- conv: barrier-free ----
  f32x4 acc[4][4];
#pragma unroll
  for (int tt = 0; tt < 4; ++tt)
#pragma unroll
    for (int oo = 0; oo < 4; ++oo) acc[tt][oo] = (f32x4){0.f, 0.f, 0.f, 0.f};
#pragma unroll
  for (int ks = 0; ks < NK; ++ks) {
    short8 a[4];
#pragma unroll
    for (int tt = 0; tt < 4; ++tt)
      a[tt] = load_a<XBF>(xf, xb, abase + ((Tb + tt) * 16 + l16) * K + ks * 32 + quad * 8);
#pragma unroll
    for (int oo = 0; oo < 4; ++oo) {
      short8 b = *(const short8*)&cwLT[((Ob + oo) * 16 + l16) * K + ks * 32 + quad * 8];
#pragma unroll
      for (int tt = 0; tt < 4; ++tt)
        acc[tt][oo] = __builtin_amdgcn_mfma_f32_16x16x32_bf16(a[tt], b, acc[tt][oo], 0, 0, 0);
    }
  }

  // ---- +cb, per-sample LN stats ----
  float ts[4] = {0.f, 0.f, 0.f, 0.f}, tq[4] = {0.f, 0.f, 0.f, 0.f};
#pragma unroll
  for (int oo = 0; oo < 4; ++oo) {
    float cbv = cb[(Ob + oo) * 16 + l16];
#pragma unroll
    for (int tt = 0; tt < 4; ++tt)
#pragma unroll
      for (int r = 0; r < 4; ++r) {
        float v = acc[tt][oo][r] + cbv;
        acc[tt][oo][r] = v;
        ts[tt] += v; tq[tt] += v * v;
      }
  }
  {
    constexpr int GPW = (S == 2) ? 2 : 1;
    float gs[2] = {0.f, 0.f}, gq[2] = {0.f, 0.f};
#pragma unroll
    for (int tt = 0; tt < 4; ++tt) {
      int gl = (S == 2) ? (tt >> 1) : 0;
      gs[gl] += ts[tt]; gq[gl] += tq[tt];
    }
#pragma unroll
    for (int j = 0; j < GPW; ++j) {
      float s = gs[j], q = gq[j];
#pragma unroll
      for (int m = 32; m >= 1; m >>= 1) { s += __shfl_xor(s, m); q += __shfl_xor(q, m); }
      if (lane == 0) {
        int g = (Tb >> GSH) + j;
        atomicAdd(&scr[256 + 2 * g], s);
        atomicAdd(&scr[257 + 2 * g], q);
      }
    }
  }
  __syncthreads();
  if (tid < SAMPLES) {
    float mu = scr[256 + 2 * tid] * INVD;
    float var = scr[257 + 2 * tid] * INVD - mu * mu;
    scr[264 + tid] = mu; scr[268 + tid] = rsqrtf(var + 1e-5f);
  }
  __syncthreads();

  // ---- fc contribution of xt ----
#pragma unroll
  for (int tt = 0; tt < 4; ++tt)
#pragma unroll
    for (int r = 0; r < 4; ++r) {
      float v = 0.f;
#pragma unroll
      for (int oo = 0; oo < 4; ++oo) v += acc[tt][oo][r] * scr[(Ob + oo) * 16 + l16];
      v += __shfl_xor(v, 1); v += __shfl_xor(v, 2);
      v += __shfl_xor(v, 4); v += __shfl_xor(v, 8);
      if (l16 == 0) atomicAdd(&part[(Tb + tt) * 16 + quad * 4 + r], v);
    }

  // ---- HT[f][t] = bf16(LN(xt)), XOR-swizzled ----
#pragma unroll
  for (int tt = 0; tt < 4; ++tt) {
    int tile = Tb + tt, g = tile >> GSH;
    float mu = scr[264 + g], rs = scr[268 + g];
    int tlb = (tile * 16) & TKM;
#pragma unroll
    for (int oo = 0; oo < 4; ++oo) {
      int f = (Ob + oo) * 16 + l16;
      int kf = (f ^ (f >> 3)) & 15;
#pragma unroll
      for (int r = 0; r < 4; ++r) {
        int t = tile * 16 + quad * 4 + r;
        int tl = tlb + quad * 4 + r;
        float hv = (acc[tt][oo][r] - mu) * rs * lg[tl * 128 + f] + lb[tl * 128 + f];
        HT[f * 128 + ((((t >> 3) ^ kf) << 3) | (t & 7))] = f2bf(hv);
      }
    }
  }
  __syncthreads();

  // ---- TM1: U = blkdiag_tril(L1) @ H ----
  f32x4 u[4][4];
#pragma unroll
  for (int tt = 0; tt < 4; ++tt)
#pragma unroll
    for (int oo = 0; oo < 4; ++oo) u[tt][oo] = (f32x4){0.f, 0.f, 0.f, 0.f};
#pragma unroll
  for (int ks = 0; ks < 4; ++ks) {
    short8 a[4]; bool act[4]; bool any = false;
#pragma unroll
    for (int tt = 0; tt < 4; ++tt) {
      int tile = Tb + tt, g = tile >> GSH;
      act[tt] = (ks * 32 <= tile * 16 + 15) && (ks * 32 + 31 >= (g << LOG2TK));
      if (act[tt]) { a[tt] = *(const short8*)&L1blk[(tile * 16 + l16) * 128 + ks * 32 + quad * 8]; any = true; }
    }
    if (!any) continue;
#pragma unroll
    for (int oo = 0; oo < 4; ++oo) {
      int f = (Ob + oo) * 16 + l16;
      int kf = (f ^ (f >> 3)) & 15;
      short8 b = *(const short8*)&HT[f * 128 + (((ks * 4 + quad) ^ kf) << 3)];
#pragma unroll
      for (int tt = 0; tt < 4; ++tt)
        if (act[tt]) u[tt][oo] = __builtin_amdgcn_mfma_f32_16x16x32_bf16(a[tt], b, u[tt][oo], 0, 0, 0);
    }
  }
  __syncthreads();

  // ---- UT = bf16(hswish(U)) ----
#pragma unroll
  for (int tt = 0; tt < 4; ++tt) {
    int tile = Tb + tt;
#pragma unroll
    for (int oo = 0; oo < 4; ++oo) {
      int f = (Ob + oo) * 16 + l16;
      int kf = (f ^ (f >> 3)) & 15;
#pragma unroll
      for (int r = 0; r < 4; ++r) {
        int t = tile * 16 + quad * 4 + r;
        HT[f * 128 + ((((t >> 3) ^ kf) << 3) | (t & 7))] = f2bf(hswish(u[tt][oo][r]));
      }
    }
  }
  __syncthreads();

  // ---- TM2: v = blkdiag_tril(L2) @ U ----
#pragma unroll
  for (int tt = 0; tt < 4; ++tt)
#pragma unroll
    for (int oo = 0; oo < 4; ++oo) u[tt][oo] = (f32x4){0.f, 0.f, 0.f, 0.f};
#pragma unroll
  for (int ks = 0; ks < 4; ++ks) {
    short8 a[4]; bool act[4]; bool any = false;
#pragma unroll
    for (int tt = 0; tt < 4; ++tt) {
      int tile = Tb + tt, g = tile >> GSH;
      act[tt] = (ks * 32 <= tile * 16 + 15) && (ks * 32 + 31 >= (g << LOG2TK));
      if (act[tt]) { a[tt] = *(const short8*)&L2blk[(tile * 16 + l16) * 128 + ks * 32 + quad * 8]; any = true; }
    }
    if (!any) continue;
#pragma unroll
    for (int oo = 0; oo < 4; ++oo) {
      int f = (Ob + oo) * 16 + l16;
      int kf = (f ^ (f >> 3)) & 15;
      short8 b = *(const short8*)&HT[f * 128 + (((ks * 4 + quad) ^ kf) << 3)];
#pragma unroll
      for (int tt = 0; tt < 4; ++tt)
        if (act[tt]) u[tt][oo] = __builtin_amdgcn_mfma_f32_16x16x32_bf16(a[tt], b, u[tt][oo], 0, 0, 0);
    }
  }

  // ---- fc contribution of v ----
#pragma unroll
  for (int tt = 0; tt < 4; ++tt)
#pragma unroll
    for (int r = 0; r < 4; ++r) {
      float v = 0.f;
#pragma unroll
      for (int oo = 0; oo < 4; ++oo) v += u[tt][oo][r] * scr[(Ob + oo) * 16 + l16];
      v += __shfl_xor(v, 1); v += __shfl_xor(v, 2);
      v += __shfl_xor(v, 4); v += __shfl_xor(v, 8);
      if (l16 == 0) atomicAdd(&part[(Tb + tt) * 16 + quad * 4 + r], v);
    }
  __syncthreads();

  if (tid < 128) {
    int g = tid >> LOG2TK, tl = tid & TKM;
    h_out[(size_t)(n0 + g) * 224 + OFF + tl] = part[tid] + fcb;
  }
}

// ---------------------------------------------------------------------------
// Stage 2
// ---------------------------------------------------------------------------
__global__ void stats_kernel(const float* __restrict__ h, float* __restrict__ stats) {
  int base = blockIdx.x * 4096;
  float s = 0.f, ss = 0.f;
  for (int j = 0; j < 16; ++j) {
    float v = h[base + j * 256 + threadIdx.x];
    s += v; ss += v * v;
  }
  int lane = threadIdx.x & 63, wave = threadIdx.x >> 6;
#pragma unroll
  for (int m = 32; m >= 1; m >>= 1) { s += __shfl_xor(s, m); ss += __shfl_xor(ss, m); }
  __shared__ float red[8];
  if (lane == 0) { red[wave * 2] = s; red[wave * 2 + 1] = ss; }
  __syncthreads();
  if (threadIdx.x == 0) {
    atomicAdd(&stats[0], red[0] + red[2] + red[4] + red[6]);
    atomicAdd(&stats[1], red[1] + red[3] + red[5] + red[7]);
  }
}

__global__ void mix1_kernel(const float* __restrict__ h,
                            const float* __restrict__ sm_lg,
                            const float* __restrict__ sm_lb,
                            const float* __restrict__ M1,
                            const float* __restrict__ stats,
                            float* __restrict__ A) {
  const int m = blockIdx.x, seg = blockIdx.y;
  const int r = threadIdx.x & 63, ch = threadIdx.x >> 6;
  const float inv = 1.f / 917504.f;
  float mu = stats[0] * inv;
  float var = stats[1] * inv - mu * mu;
  float rsig = rsqrtf(var + 1e-5f);
  float acc = 0.f;
  int n0 = seg * 1024 + ch * 256;
  for (int i = 0; i < 256; ++i) {
    int n = n0 + i;
    float hn = (h[n * 224 + m] - mu) * rsig * sm_lg[n * 224 + m] + sm_lb[n * 224 + m];
    acc += M1[r * 4096 + n] * hn;
  }
  __shared__ float red[256];
  red[threadIdx.x] = acc;
  __syncthreads();
  if (threadIdx.x < 64)
    atomicAdd(&A[threadIdx.x * 224 + m],
              red[threadIdx.x] + red[64 + threadIdx.x] + red[128 + threadIdx.x] + red[192 + threadIdx.x]);
}

__global__ void mix2_kernel(const float* __restrict__ A,
                            const float* __restrict__ sm_fc_w,
                            float* __restrict__ cvec) {
  int r = threadIdx.x & 63, ch = threadIdx.x >> 6;
  float acc = 0.f;
  for (int j = ch; j < 224; j += 4)
    acc += hswish(A[r * 224 + j]) * sm_fc_w[224 + j];
  __shared__ float red[256];
  red[threadIdx.x] = acc;
  __syncthreads();
  if (threadIdx.x < 64)
    cvec[threadIdx.x] = red[threadIdx.x] + red[64 + threadIdx.x] + red[128 + threadIdx.x] + red[192 + threadIdx.x];
}

__global__ void out_kernel(const float* __restrict__ h,
                           const float* __restrict__ M2,
                           const float* __restrict__ cvec,
                           const float* __restrict__ sm_fc_w,
                           const float* __restrict__ sm_fc_b,
                           float* __restrict__ out) {
  int wave = threadIdx.x >> 6, lane = threadIdx.x & 63;
  int n = blockIdx.x * 4 + wave;
  float acc = M2[n * 64 + lane] * cvec[lane];
  for (int j = lane; j < 224; j += 64)
    acc += h[n * 224 + j] * (sm_fc_w[j] + sm_fc_w[224 + j]);
#pragma unroll
  for (int m = 32; m >= 1; m >>= 1) acc += __shfl_xor(acc, m);
  if (lane == 0) out[n] = acc + sm_fc_b[0];
}

// ---------------------------------------------------------------------------
extern "C" void kernel_launch(void* const* d_in, const int* in_sizes, int n_in,
                              void* d_out, int out_size, void* d_ws, size_t ws_size,
                              hipStream_t stream) {
  const float* x      = (const float*)d_in[0];
  const float* cw0    = (const float*)d_in[1];
  const float* cb0    = (const float*)d_in[2];
  const float* lg0    = (const float*)d_in[3];
  const float* lb0    = (const float*)d_in[4];
  const float* L1_0   = (const float*)d_in[5];
  const float* L2_0   = (const float*)d_in[6];
  const float* cw1    = (const float*)d_in[7];
  const float* cb1    = (const float*)d_in[8];
  const float* lg1    = (const float*)d_in[9];
  const float* lb1    = (const float*)d_in[10];
  const float* L1_1   = (const float*)d_in[11];
  const float* L2_1   = (const float*)d_in[12];
  const float* cw2    = (const float*)d_in[13];
  const float* cb2    = (const float*)d_in[14];
  const float* lg2    = (const float*)d_in[15];
  const float* lb2    = (const float*)d_in[16];
  const float* L1_2   = (const float*)d_in[17];
  const float* L2_2   = (const float*)d_in[18];
  const float* fc_w   = (const float*)d_in[19];
  const float* fc_b   = (const float*)d_in[20];
  const float* sm_lg  = (const float*)d_in[21];
  const float* sm_lb  = (const float*)d_in[22];
  const float* M1     = (const float*)d_in[23];
  const float* M2     = (const float*)d_in[24];
  const float* sm_fc_w = (const float*)d_in[25];
  const float* sm_fc_b = (const float*)d_in[26];

  char* ws = (char*)d_ws;
  unsigned short* ws16 = (unsigned short*)ws;          // 212992 elems = 425984 B
  float* h     = (float*)(ws + 425984);                // 3670016 B -> ends 4096000
  float* stats = (float*)(ws + 4096000);               // 8 B (+pad)
  float* A     = (float*)(ws + 4096256);               // 57344 B -> 4153600
  float* cvec  = (float*)(ws + 4153600);               // 256 B -> 4153856
  unsigned short* xbf = (unsigned short*)(ws + 4194304); // 134217728 B -> 138412032
  const bool use_xbf = ws_size >= 138412032ULL;

  const unsigned short* cwLT0 = ws16;
  const unsigned short* cwLT1 = ws16 + 16384;
  const unsigned short* cwLT2 = ws16 + 49152;
  const unsigned short* L1b0 = ws16 + 114688;
  const unsigned short* L2b0 = ws16 + 131072;
  const unsigned short* L1b1 = ws16 + 147456;
  const unsigned short* L2b1 = ws16 + 163840;
  const unsigned short* L1b2 = ws16 + 180224;
  const unsigned short* L2b2 = ws16 + 196608;

  prep_kernel<<<832, 256, 0, stream>>>(cw0, cw1, cw2, L1_0, L2_0, L1_1, L2_1, L1_2, L2_2, ws16);

  if (use_xbf) {
    xcvt_kernel<<<16384, 256, 0, stream>>>(x, xbf);
    s1_tile<0, true><<<4096, 256, 0, stream>>>(x, xbf, cb0, lg0, lb0, fc_w, fc_b, cwLT0, L1b0, L2b0, h);
    s1_tile<1, true><<<2048, 256, 0, stream>>>(x, xbf, cb1, lg1, lb1, fc_w, fc_b, cwLT1, L1b1, L2b1, h);
    s1_tile<2, true><<<1024, 256, 0, stream>>>(x, xbf, cb2, lg2, lb2, fc_w, fc_b, cwLT2, L1b2, L2b2, h);
  } else {
    s1_tile<0, false><<<4096, 256, 0, stream>>>(x, xbf, cb0, lg0, lb0, fc_w, fc_b, cwLT0, L1b0, L2b0, h);
    s1_tile<1, false><<<2048, 256, 0, stream>>>(x, xbf, cb1, lg1, lb1, fc_w, fc_b, cwLT1, L1b1, L2b1, h);
    s1_tile<2, false><<<1024, 256, 0, stream>>>(x, xbf, cb2, lg2, lb2, fc_w, fc_b, cwLT2, L1b2, L2b2, h);
  }

  hipMemsetAsync(ws + 4096000, 0, 57600, stream);
  stats_kernel<<<224, 256, 0, stream>>>(h, stats);
  mix1_kernel<<<dim3(224, 4), 256, 0, stream>>>(h, sm_lg, sm_lb, M1, stats, A);
  mix2_kernel<<<1, 256, 0, stream>>>(A, sm_fc_w, cvec);
  out_kernel<<<1024, 256, 0, stream>>>(h, M2, cvec, sm_fc_w, sm_fc_b, (float*)d_out);
}